// Round 2
// baseline (683.979 us; speedup 1.0000x reference)
//
#include <hip/hip_runtime.h>
#include <math.h>

// Encoder: 3x (gather-scatter conv + linear + ELU) then per-graph FC.
// Strategy: build CSR by dst per call (int atomics only), convs become
// gathers with register accumulation (no fp32 atomics), FC1 split-K
// streaming of the 128MB weight at HBM BW.

#define NODES   65536
#define NGRAPH  16
#define EDGES   2097152
#define FIN     16
#define HID     32
#define KDIM    131072          // 4096*32 per-graph flattened
#define FCH     256
#define LATENT  64
#define FCB     512             // fc1 split-K blocks
#define KSLICE  (KDIM / FCB)    // 256

__device__ __forceinline__ float elu_f(float v) { return v > 0.0f ? v : expf(v) - 1.0f; }

// ---------------- CSR build ----------------

__global__ void zero_int4_kernel(int4* __restrict__ p) {
  p[blockIdx.x * blockDim.x + threadIdx.x] = make_int4(0, 0, 0, 0);
}

__global__ void hist_kernel(const int* __restrict__ ei, int* __restrict__ cnt) {
  int t = blockIdx.x * blockDim.x + threadIdx.x;
  atomicAdd(&cnt[ei[EDGES + t]], 1);
}

// 64 blocks x 1024 threads: per-block inclusive scan of 1024 counts
__global__ __launch_bounds__(1024) void scan_block_kernel(const int* __restrict__ cnt,
                                                          int* __restrict__ row_ptr,
                                                          int* __restrict__ bsum) {
  __shared__ int s[1024];
  int i = blockIdx.x * 1024 + threadIdx.x;
  int v = cnt[i];
  s[threadIdx.x] = v;
  __syncthreads();
  for (int off = 1; off < 1024; off <<= 1) {
    int t = (threadIdx.x >= off) ? s[threadIdx.x - off] : 0;
    __syncthreads();
    s[threadIdx.x] += t;
    __syncthreads();
  }
  row_ptr[i + 1] = s[threadIdx.x];          // pre-offset inclusive scan
  if (threadIdx.x == 1023) bsum[blockIdx.x] = s[1023];
}

// 1 block, 64 threads (one wave): exclusive scan of 64 block sums, in place
__global__ void scan_top_kernel(int* __restrict__ bsum) {
  int lane = threadIdx.x;
  int own = bsum[lane];
  int v = own;
  for (int off = 1; off < 64; off <<= 1) {
    int t = __shfl_up(v, off);
    if (lane >= off) v += t;
  }
  bsum[lane] = v - own;                     // exclusive block offset
}

__global__ void scan_fix_kernel(const int* __restrict__ cnt, int* __restrict__ row_ptr,
                                int* __restrict__ cursor, const int* __restrict__ bsum) {
  int i = blockIdx.x * blockDim.x + threadIdx.x;   // [0, NODES)
  int v = row_ptr[i + 1] + bsum[i >> 10];
  row_ptr[i + 1] = v;
  cursor[i] = v - cnt[i];                   // row start
  if (i == 0) row_ptr[0] = 0;
}

__global__ void fill_kernel(const int* __restrict__ ei, const float* __restrict__ ew,
                            int* __restrict__ cursor, int* __restrict__ csr_src,
                            float* __restrict__ csr_w) {
  int t = blockIdx.x * blockDim.x + threadIdx.x;
  int dst = ei[EDGES + t];
  int pos = atomicAdd(&cursor[dst], 1);
  csr_src[pos] = ei[t];
  csr_w[pos] = ew[t];
}

// ---------------- conv aggregation (gather form, no atomics) ----------------
// CH = float4 chunks per feature row (4 for C=16, 8 for C=32).
// CH lanes cooperate on one node; each lane owns 4 channels.
template <int CH>
__global__ void gather_kernel(const float* __restrict__ h, const int* __restrict__ row_ptr,
                              const int* __restrict__ csr_src, const float* __restrict__ csr_w,
                              float* __restrict__ agg) {
  int t = blockIdx.x * blockDim.x + threadIdx.x;
  int node = t / CH;
  int q = t % CH;
  int jb = row_ptr[node], je = row_ptr[node + 1];
  float4 acc = make_float4(0.f, 0.f, 0.f, 0.f);
  int j = jb;
  for (; j + 1 < je; j += 2) {              // unroll-2 for memory-level parallelism
    int s0 = csr_src[j], s1 = csr_src[j + 1];
    float w0 = csr_w[j], w1 = csr_w[j + 1];
    float4 a = *reinterpret_cast<const float4*>(h + (size_t)s0 * (CH * 4) + q * 4);
    float4 b = *reinterpret_cast<const float4*>(h + (size_t)s1 * (CH * 4) + q * 4);
    acc.x += a.x * w0 + b.x * w1;
    acc.y += a.y * w0 + b.y * w1;
    acc.z += a.z * w0 + b.z * w1;
    acc.w += a.w * w0 + b.w * w1;
  }
  if (j < je) {
    int s0 = csr_src[j];
    float w0 = csr_w[j];
    float4 a = *reinterpret_cast<const float4*>(h + (size_t)s0 * (CH * 4) + q * 4);
    acc.x += a.x * w0; acc.y += a.y * w0; acc.z += a.z * w0; acc.w += a.w * w0;
  }
  *reinterpret_cast<float4*>(agg + (size_t)node * (CH * 4) + q * 4) = acc;
}

// ---------------- per-node linear + ELU ----------------
template <int IN>
__global__ void lin_elu_kernel(const float* __restrict__ agg, const float* __restrict__ W,
                               const float* __restrict__ bias, float* __restrict__ out) {
  __shared__ float sW[IN * HID];
  __shared__ float sb[HID];
  for (int i = threadIdx.x; i < IN * HID; i += blockDim.x) sW[i] = W[i];
  if (threadIdx.x < HID) sb[threadIdx.x] = bias[threadIdx.x];
  __syncthreads();
  int n = blockIdx.x * blockDim.x + threadIdx.x;
  float a[IN];
#pragma unroll
  for (int i = 0; i < IN; i += 4) {
    float4 v = *reinterpret_cast<const float4*>(agg + (size_t)n * IN + i);
    a[i] = v.x; a[i + 1] = v.y; a[i + 2] = v.z; a[i + 3] = v.w;
  }
  float o[HID];
#pragma unroll
  for (int c = 0; c < HID; ++c) o[c] = sb[c];
#pragma unroll
  for (int i = 0; i < IN; ++i) {
    float ai = a[i];
#pragma unroll
    for (int c = 0; c < HID; ++c) o[c] += ai * sW[i * HID + c];
  }
#pragma unroll
  for (int c = 0; c < HID; c += 4) {
    float4 v = make_float4(elu_f(o[c]), elu_f(o[c + 1]), elu_f(o[c + 2]), elu_f(o[c + 3]));
    *reinterpret_cast<float4*>(out + (size_t)n * HID + c) = v;
  }
}

// ---------------- FC1 split-K ----------------
// Grid FCB blocks x 256 threads. Wave w handles k = k0 + w (mod 4); lane owns 4 cols.
__global__ void fc1_partial_kernel(const float* __restrict__ h, const float* __restrict__ W,
                                   float* __restrict__ part) {
  __shared__ float red[NGRAPH * FCH];      // 16 KB
  const int tid = threadIdx.x;
  const int lane = tid & 63;
  const int wv = tid >> 6;
  const int k0 = blockIdx.x * KSLICE;
  float4 acc[NGRAPH];
#pragma unroll
  for (int g = 0; g < NGRAPH; ++g) acc[g] = make_float4(0.f, 0.f, 0.f, 0.f);
  for (int kk = wv; kk < KSLICE; kk += 4) {
    const int k = k0 + kk;
    const float4 wr = *reinterpret_cast<const float4*>(W + (size_t)k * FCH + lane * 4);
#pragma unroll
    for (int g = 0; g < NGRAPH; ++g) {
      const float hv = h[(size_t)g * KDIM + k];  // wave-uniform -> 1 request
      acc[g].x += wr.x * hv; acc[g].y += wr.y * hv;
      acc[g].z += wr.z * hv; acc[g].w += wr.w * hv;
    }
  }
  for (int i = tid; i < NGRAPH * FCH; i += blockDim.x) red[i] = 0.f;
  __syncthreads();
#pragma unroll
  for (int g = 0; g < NGRAPH; ++g) {
    atomicAdd(&red[g * FCH + lane * 4 + 0], acc[g].x);
    atomicAdd(&red[g * FCH + lane * 4 + 1], acc[g].y);
    atomicAdd(&red[g * FCH + lane * 4 + 2], acc[g].z);
    atomicAdd(&red[g * FCH + lane * 4 + 3], acc[g].w);
  }
  __syncthreads();
  float* dst = part + (size_t)blockIdx.x * (NGRAPH * FCH);
  for (int i = tid; i < NGRAPH * FCH; i += blockDim.x) dst[i] = red[i];
}

// 64 blocks: (g, 64-col tile). Reduce over FCB partials, +bias, ELU.
__global__ void fc1_reduce_kernel(const float* __restrict__ part, const float* __restrict__ bfc1,
                                  float* __restrict__ act) {
  __shared__ float red[4][64];
  const int g = blockIdx.x >> 2;
  const int c0 = (blockIdx.x & 3) * 64;
  const int lane = threadIdx.x & 63;
  const int wv = threadIdx.x >> 6;
  const int c = c0 + lane;
  float s = 0.f;
#pragma unroll 8
  for (int b = wv; b < FCB; b += 4) s += part[(size_t)b * (NGRAPH * FCH) + g * FCH + c];
  red[wv][lane] = s;
  __syncthreads();
  if (wv == 0) {
    float v = red[0][lane] + red[1][lane] + red[2][lane] + red[3][lane];
    act[g * FCH + c] = elu_f(v + bfc1[c]);
  }
}

// 16 blocks x 64 threads: [16,256] @ [256,64] + bias
__global__ void fc2_kernel(const float* __restrict__ act, const float* __restrict__ Wfc2,
                           const float* __restrict__ bfc2, float* __restrict__ out) {
  const int g = blockIdx.x;
  const int c = threadIdx.x;
  float o = bfc2[c];
#pragma unroll 8
  for (int i = 0; i < FCH; ++i) o += act[g * FCH + i] * Wfc2[i * LATENT + c];
  out[g * LATENT + c] = o;
}

extern "C" void kernel_launch(void* const* d_in, const int* in_sizes, int n_in,
                              void* d_out, int out_size, void* d_ws, size_t ws_size,
                              hipStream_t stream) {
  const float* x    = (const float*)d_in[0];
  const float* ea   = (const float*)d_in[1];
  const float* W1   = (const float*)d_in[2];
  const float* b1   = (const float*)d_in[3];
  const float* W2   = (const float*)d_in[4];
  const float* b2   = (const float*)d_in[5];
  const float* W3   = (const float*)d_in[6];
  const float* b3   = (const float*)d_in[7];
  const float* Wfc1 = (const float*)d_in[8];
  const float* bfc1 = (const float*)d_in[9];
  const float* Wfc2 = (const float*)d_in[10];
  const float* bfc2 = (const float*)d_in[11];
  const int*   ei   = (const int*)d_in[12];
  float* out = (float*)d_out;

  char* w = (char*)d_ws;
  float* agg     = (float*)(w + 0);                          // 8 MB
  float* hA      = (float*)(w + (size_t)(8 << 20));          // 8 MB (h1 then h3)
  float* hB      = (float*)(w + (size_t)(16 << 20));         // 8 MB (h2 then fc partials)
  int*   csr_src = (int*)  (w + (size_t)(24 << 20));         // 8 MB
  float* csr_w   = (float*)(w + (size_t)(32 << 20));         // 8 MB
  int*   cnt     = (int*)  (w + (size_t)(40 << 20));         // 256 KB
  int*   row_ptr = (int*)  (w + (size_t)(40 << 20) + (260u << 10)); // 256 KB + 4
  int*   cursor  = (int*)  (w + (size_t)(40 << 20) + (524u << 10)); // 256 KB
  int*   bsum    = (int*)  (w + (size_t)(40 << 20) + (788u << 10)); // 64 ints
  float* act     = (float*)(w + (size_t)(40 << 20) + (792u << 10)); // 16 KB
  float* part    = hB;

  // ---- CSR build ----
  zero_int4_kernel<<<NODES / 4 / 256, 256, 0, stream>>>((int4*)cnt);
  hist_kernel<<<EDGES / 256, 256, 0, stream>>>(ei, cnt);
  scan_block_kernel<<<NODES / 1024, 1024, 0, stream>>>(cnt, row_ptr, bsum);
  scan_top_kernel<<<1, 64, 0, stream>>>(bsum);
  scan_fix_kernel<<<NODES / 256, 256, 0, stream>>>(cnt, row_ptr, cursor, bsum);
  fill_kernel<<<EDGES / 256, 256, 0, stream>>>(ei, ea, cursor, csr_src, csr_w);

  // ---- conv1: x[N,16] -> hA[N,32] ----
  gather_kernel<4><<<NODES * 4 / 256, 256, 0, stream>>>(x, row_ptr, csr_src, csr_w, agg);
  lin_elu_kernel<16><<<NODES / 256, 256, 0, stream>>>(agg, W1, b1, hA);
  // ---- conv2: hA -> hB ----
  gather_kernel<8><<<NODES * 8 / 256, 256, 0, stream>>>(hA, row_ptr, csr_src, csr_w, agg);
  lin_elu_kernel<32><<<NODES / 256, 256, 0, stream>>>(agg, W2, b2, hB);
  // ---- conv3: hB -> hA ----
  gather_kernel<8><<<NODES * 8 / 256, 256, 0, stream>>>(hB, row_ptr, csr_src, csr_w, agg);
  lin_elu_kernel<32><<<NODES / 256, 256, 0, stream>>>(agg, W3, b3, hA);

  // ---- FC head ----
  fc1_partial_kernel<<<FCB, 256, 0, stream>>>(hA, Wfc1, part);
  fc1_reduce_kernel<<<64, 256, 0, stream>>>(part, bfc1, act);
  fc2_kernel<<<NGRAPH, 64, 0, stream>>>(act, Wfc2, bfc2, out);
}